// Round 5
// baseline (283.933 us; speedup 1.0000x reference)
//
#include <hip/hip_runtime.h>

#define BLOCK 256
#define GRID  2048   // persistent: 8 blocks/CU x 256 CUs

// Native clang vector type: __builtin_nontemporal_store requires a pointer to
// a scalar or NATIVE vector type — HIP's float4 (HIP_vector_type class) is
// rejected (round-4 compile error). Same 16B layout, bit-identical stores.
typedef float f32x4 __attribute__((ext_vector_type(4)));

// ln(x) via v_log_f32 (log2, ~1 ulp) * ln2. Inputs here are >= ~5e-3, well
// away from denormal trouble. Absolute output threshold is 0.675 on values
// up to ~454 -> ~1.5e-3 relative budget; these approximations are ~1e-7.
__device__ __forceinline__ float fast_ln(float x) {
    return 0.69314718056f * __builtin_amdgcn_logf(x);
}
__device__ __forceinline__ float fast_rcp(float x) {
    return __builtin_amdgcn_rcpf(x);
}
__device__ __forceinline__ float fast_rsq(float x) {
    return __builtin_amdgcn_rsqf(x);
}

// ds_bpermute_b32: dst lane i <- src register of lane (addr>>2). Crossbar
// gather of the lane-resident parameter table; N_RELS == 64 == wavefront.
// Must only execute with all 64 lanes active (reads source lane's register).
__device__ __forceinline__ float bperm(int ab, float v) {
    return __int_as_float(__builtin_amdgcn_ds_bpermute(ab, __float_as_int(v)));
}

// Faithful sparsemax for d=3 (Martins & Astudillo 2016), matching the
// reference: sort desc, cumsum, ksup = sum of support booleans,
// tau = (cs[ksup-1]-1)/ksup, out = max(z - tau, 0).
__device__ __forceinline__ void sparsemax3(float z0, float z1, float z2,
                                           float& o0, float& o1, float& o2) {
    float lo01 = fminf(z0, z1), hi01 = fmaxf(z0, z1);
    float s2 = fminf(lo01, z2);          // min of all
    float mx = fmaxf(lo01, z2);
    float s0 = fmaxf(hi01, mx);          // max of all
    float s1 = fminf(hi01, mx);          // middle
    float cs2 = s0 + s1;
    float cs3 = cs2 + s2;
    // k=1 support condition (1 + s0 > s0) is always true.
    bool k2 = (1.0f + 2.0f * s1 > cs2);
    bool k3 = (1.0f + 3.0f * s2 > cs3);
    int k = 1 + (int)k2 + (int)k3;
    float csk = (k == 1) ? s0 : ((k == 2) ? cs2 : cs3);
    float rk  = (k == 1) ? 1.0f : ((k == 2) ? 0.5f : 0.33333334f);
    float tau = (csk - 1.0f) * rk;
    o0 = fmaxf(z0 - tau, 0.0f);
    o1 = fmaxf(z1 - tau, 0.0f);
    o2 = fmaxf(z2 - tau, 0.0f);
}

__device__ __forceinline__ void edge_core(
    float p0, float p1, float p2,
    float q0, float q1, float q2,
    float m00, float m01, float m02,
    float m10, float m11, float m12,
    float m20, float m21, float m22,
    float b0, float b1, float b2,
    float zeps, float sf,
    float& a0o, float& a1o, float& a2o)
{
    float c0 = m00 * q0 + m01 * q1 + m02 * q2;
    float c1 = m10 * q0 + m11 * q1 + m12 * q2;
    float c2 = m20 * q0 + m21 * q1 + m22 * q2;
    sparsemax3(c0, c1, c2, c0, c1, c2);
    // Reference applies sparsemax to c twice; it is an exactly idempotent
    // Euclidean projection -> second application changes ~ulp. Dropped.
    sparsemax3(p0, p1, p2, p0, p1, p2);
    float a0 = p0 + b0 * (c0 - p0);
    float a1 = p1 + b1 * (c1 - p1);
    float a2 = p2 + b2 * (c2 - p2);
    float z0 = fmaxf(p0 + c0, zeps);
    float z1 = fmaxf(p1 + c1, zeps);
    float z2 = fmaxf(p2 + c2, zeps);
    float rs = fast_rcp(z0 + z1 + z2);
    z0 *= rs; z1 *= rs; z2 *= rs;
    float ent = -(z0 * fast_ln(z0) + z1 * fast_ln(z1) + z2 * fast_ln(z2));
    float dot = p0 * c0 + p1 * c1 + p2 * c2;
    float pp = p0 * p0 + p1 * p1 + p2 * p2;
    float cc = c0 * c0 + c1 * c1 + c2 * c2;
    float cosv = 0.1f + dot * fast_rsq(fmaxf(pp * cc, 1e-20f));
    float scale = sf * cosv * fast_rcp(ent);
    a0o = fmaxf(a0 * scale, 0.001f);
    a1o = fmaxf(a1 * scale, 0.001f);
    a2o = fmaxf(a2 * scale, 0.001f);
}

__global__ __launch_bounds__(BLOCK) void alpha_kernel(
    const float* __restrict__ prnt, const float* __restrict__ child,
    const float* __restrict__ Mg, const float* __restrict__ betag,
    const float* __restrict__ zeps_p, const float* __restrict__ sf_p,
    const int* __restrict__ rels, float* __restrict__ out, int n_edges)
{
    // Lane-resident parameter table: lane l holds M[l] (9 regs) + beta[l]
    // (3 regs). Persistent grid: loaded once per thread for ~16 edges.
    const int lane = threadIdx.x & 63;
    float mt[9], bt[3];
    {
        const float* mr = Mg + lane * 9;
#pragma unroll
        for (int k = 0; k < 9; ++k) mt[k] = mr[k];
        const float* br = betag + lane * 3;
#pragma unroll
        for (int k = 0; k < 3; ++k) bt[k] = br[k];
    }

    const float zeps = zeps_p[0];
    const float sf   = sf_p[0];
    const int nt4 = n_edges >> 2;            // full groups of 4 edges

    if (nt4 > 0) {
        const int S  = GRID * BLOCK;         // chunk stride
        const int t0 = blockIdx.x * BLOCK + threadIdx.x;
        const int iters = (nt4 + S - 1) / S; // UNIFORM across the whole grid:
                                             // every branch below is wave-uniform,
                                             // so bpermute always sees 64 active lanes.
        const float4* p4  = (const float4*)prnt;
        const float4* c4  = (const float4*)child;
        const int4*   r4p = (const int4*)rels;
        f32x4* o4 = reinterpret_cast<f32x4*>(out);

        // Ping-pong pipeline registers (2 chunks in flight).
        float4 Apa, Apb, Apc, Aca, Acb, Acc; int4 Ar;
        float4 Bpa, Bpb, Bpc, Bca, Bcb, Bcc; int4 Br;

        auto load_chunk = [&](int idx, float4& pa, float4& pb, float4& pc,
                              float4& ca, float4& cb, float4& cc, int4& rr) {
            rr = r4p[idx];
            pa = p4[3 * idx + 0]; pb = p4[3 * idx + 1]; pc = p4[3 * idx + 2];
            ca = c4[3 * idx + 0]; cb = c4[3 * idx + 1]; cc = c4[3 * idx + 2];
        };

        auto work_chunk = [&](int k, const float4& pa, const float4& pb,
                              const float4& pc, const float4& ca,
                              const float4& cb, const float4& cc,
                              const int4& rr) {
            float P[12] = {pa.x, pa.y, pa.z, pa.w, pb.x, pb.y, pb.z, pb.w,
                           pc.x, pc.y, pc.z, pc.w};
            float C[12] = {ca.x, ca.y, ca.z, ca.w, cb.x, cb.y, cb.z, cb.w,
                           cc.x, cc.y, cc.z, cc.w};
            int R[4] = {rr.x, rr.y, rr.z, rr.w};
            float O[12];
#pragma unroll
            for (int e = 0; e < 4; ++e) {
                int ab = R[e] << 2;          // byte index for bpermute
                float g0 = bperm(ab, mt[0]), g1 = bperm(ab, mt[1]), g2 = bperm(ab, mt[2]);
                float g3 = bperm(ab, mt[3]), g4 = bperm(ab, mt[4]), g5 = bperm(ab, mt[5]);
                float g6 = bperm(ab, mt[6]), g7 = bperm(ab, mt[7]), g8 = bperm(ab, mt[8]);
                float h0 = bperm(ab, bt[0]), h1 = bperm(ab, bt[1]), h2 = bperm(ab, bt[2]);
                edge_core(P[3 * e], P[3 * e + 1], P[3 * e + 2],
                          C[3 * e], C[3 * e + 1], C[3 * e + 2],
                          g0, g1, g2, g3, g4, g5, g6, g7, g8,
                          h0, h1, h2, zeps, sf,
                          O[3 * e], O[3 * e + 1], O[3 * e + 2]);
            }
            int i = t0 + k * S;
            if (i < nt4) {                   // per-lane guard: stores only
                f32x4 oa = {O[0], O[1], O[2],  O[3]};
                f32x4 ob = {O[4], O[5], O[6],  O[7]};
                f32x4 oc = {O[8], O[9], O[10], O[11]};
                // Nontemporal: keep the 96 MB output stream out of L2/L3 so
                // the 224 MB input set stays LLC-resident across iterations.
                __builtin_nontemporal_store(oa, &o4[3 * i + 0]);
                __builtin_nontemporal_store(ob, &o4[3 * i + 1]);
                __builtin_nontemporal_store(oc, &o4[3 * i + 2]);
            }
        };

        // Prologue: chunk 0 in flight.
        load_chunk(min(t0, nt4 - 1), Apa, Apb, Apc, Aca, Acb, Acc, Ar);

        for (int k = 0; k < iters; k += 2) {
            const bool have1 = (k + 1 < iters);      // uniform
            if (have1)
                load_chunk(min(t0 + (k + 1) * S, nt4 - 1),
                           Bpa, Bpb, Bpc, Bca, Bcb, Bcc, Br);
            work_chunk(k, Apa, Apb, Apc, Aca, Acb, Acc, Ar);
            if (have1) {
                if (k + 2 < iters)                   // uniform
                    load_chunk(min(t0 + (k + 2) * S, nt4 - 1),
                               Apa, Apb, Apc, Aca, Acb, Acc, Ar);
                work_chunk(k + 1, Bpa, Bpb, Bpc, Bca, Bcb, Bcc, Br);
            }
        }
    }

    // Defensive scalar tail for n_edges % 4 (none at N=8M). Divergent region:
    // NO cross-lane ops — read M/beta straight from global.
    if (blockIdx.x == 0 && threadIdx.x == 0) {
        for (int e = (n_edges >> 2) * 4; e < n_edges; ++e) {
            int r = rels[e];
            const float* m = Mg + r * 9;
            const float* b = betag + r * 3;
            float a0, a1, a2;
            edge_core(prnt[3 * e], prnt[3 * e + 1], prnt[3 * e + 2],
                      child[3 * e], child[3 * e + 1], child[3 * e + 2],
                      m[0], m[1], m[2], m[3], m[4], m[5], m[6], m[7], m[8],
                      b[0], b[1], b[2], zeps, sf, a0, a1, a2);
            out[3 * e] = a0; out[3 * e + 1] = a1; out[3 * e + 2] = a2;
        }
    }
}

extern "C" void kernel_launch(void* const* d_in, const int* in_sizes, int n_in,
                              void* d_out, int out_size, void* d_ws, size_t ws_size,
                              hipStream_t stream) {
    const float* prnt  = (const float*)d_in[0];
    const float* child = (const float*)d_in[1];
    const float* Mg    = (const float*)d_in[2];
    const float* betag = (const float*)d_in[3];
    const float* zeps  = (const float*)d_in[4];
    const float* sf    = (const float*)d_in[5];
    const int*   rels  = (const int*)d_in[6];
    float* out = (float*)d_out;

    int n_edges = in_sizes[0] / 3;
    alpha_kernel<<<GRID, BLOCK, 0, stream>>>(
        prnt, child, Mg, betag, zeps, sf, rels, out, n_edges);
}

// Round 6
// 263.466 us; speedup vs baseline: 1.0777x; 1.0777x over previous
//
#include <hip/hip_runtime.h>

#define BLOCK 256
#define NWAVES (BLOCK / 64)

// Native clang vector: bit-identical to float4, usable with builtins.
typedef float f32x4 __attribute__((ext_vector_type(4)));

// ln(x) via v_log_f32 (log2, ~1 ulp) * ln2. Inputs >= ~5e-3; output absmax
// budget 0.675 on values up to ~454 -> ~1.5e-3 relative; these are ~1e-7.
__device__ __forceinline__ float fast_ln(float x) {
    return 0.69314718056f * __builtin_amdgcn_logf(x);
}
__device__ __forceinline__ float fast_rcp(float x) {
    return __builtin_amdgcn_rcpf(x);
}
__device__ __forceinline__ float fast_rsq(float x) {
    return __builtin_amdgcn_rsqf(x);
}

// ds_bpermute_b32 crossbar gather of the lane-resident parameter table;
// N_RELS == 64 == wavefront. Execute only with all 64 lanes active.
__device__ __forceinline__ float bperm(int ab, float v) {
    return __int_as_float(__builtin_amdgcn_ds_bpermute(ab, __float_as_int(v)));
}

// Async global->LDS DMA, 16 B/lane. LDS dest = wave-uniform base + lane*16
// (linear); global src is per-lane. Tracked by vmcnt.
__device__ __forceinline__ void gload_lds16(const float* g, float* l) {
    __builtin_amdgcn_global_load_lds(
        (const __attribute__((address_space(1))) unsigned int*)g,
        (__attribute__((address_space(3))) unsigned int*)l,
        16, 0, 0);
}

// Faithful sparsemax for d=3 (Martins & Astudillo 2016): sort desc, cumsum,
// ksup = sum of support booleans, tau = (cs[ksup-1]-1)/ksup, max(z-tau,0).
__device__ __forceinline__ void sparsemax3(float z0, float z1, float z2,
                                           float& o0, float& o1, float& o2) {
    float lo01 = fminf(z0, z1), hi01 = fmaxf(z0, z1);
    float s2 = fminf(lo01, z2);          // min of all
    float mx = fmaxf(lo01, z2);
    float s0 = fmaxf(hi01, mx);          // max of all
    float s1 = fminf(hi01, mx);          // middle
    float cs2 = s0 + s1;
    float cs3 = cs2 + s2;
    bool k2 = (1.0f + 2.0f * s1 > cs2);
    bool k3 = (1.0f + 3.0f * s2 > cs3);
    int k = 1 + (int)k2 + (int)k3;
    float csk = (k == 1) ? s0 : ((k == 2) ? cs2 : cs3);
    float rk  = (k == 1) ? 1.0f : ((k == 2) ? 0.5f : 0.33333334f);
    float tau = (csk - 1.0f) * rk;
    o0 = fmaxf(z0 - tau, 0.0f);
    o1 = fmaxf(z1 - tau, 0.0f);
    o2 = fmaxf(z2 - tau, 0.0f);
}

__device__ __forceinline__ void edge_core(
    float p0, float p1, float p2,
    float q0, float q1, float q2,
    float m00, float m01, float m02,
    float m10, float m11, float m12,
    float m20, float m21, float m22,
    float b0, float b1, float b2,
    float zeps, float sf,
    float& a0o, float& a1o, float& a2o)
{
    float c0 = m00 * q0 + m01 * q1 + m02 * q2;
    float c1 = m10 * q0 + m11 * q1 + m12 * q2;
    float c2 = m20 * q0 + m21 * q1 + m22 * q2;
    sparsemax3(c0, c1, c2, c0, c1, c2);
    // Reference applies sparsemax to c twice; exactly idempotent projection,
    // second application changes ~ulp. Dropped.
    sparsemax3(p0, p1, p2, p0, p1, p2);
    float a0 = p0 + b0 * (c0 - p0);
    float a1 = p1 + b1 * (c1 - p1);
    float a2 = p2 + b2 * (c2 - p2);
    float z0 = fmaxf(p0 + c0, zeps);
    float z1 = fmaxf(p1 + c1, zeps);
    float z2 = fmaxf(p2 + c2, zeps);
    float rs = fast_rcp(z0 + z1 + z2);
    z0 *= rs; z1 *= rs; z2 *= rs;
    float ent = -(z0 * fast_ln(z0) + z1 * fast_ln(z1) + z2 * fast_ln(z2));
    float dot = p0 * c0 + p1 * c1 + p2 * c2;
    float pp = p0 * p0 + p1 * p1 + p2 * p2;
    float cc = c0 * c0 + c1 * c1 + c2 * c2;
    float cosv = 0.1f + dot * fast_rsq(fmaxf(pp * cc, 1e-20f));
    float scale = sf * cosv * fast_rcp(ent);
    a0o = fmaxf(a0 * scale, 0.001f);
    a1o = fmaxf(a1 * scale, 0.001f);
    a2o = fmaxf(a2 * scale, 0.001f);
}

// __launch_bounds__(256, 6): 6 waves/EU floor caps VGPR ~80 so the LDS
// footprint (24.6 KB/block -> 6 blocks/CU = 24 waves) is the occupancy
// limit, not registers (round-5 lesson: 72 VGPR halved waves/SIMD).
__global__ __launch_bounds__(BLOCK, 6) void alpha_kernel(
    const float* __restrict__ prnt, const float* __restrict__ child,
    const float* __restrict__ Mg, const float* __restrict__ betag,
    const float* __restrict__ zeps_p, const float* __restrict__ sf_p,
    const int* __restrict__ rels, float* __restrict__ out, int n_edges)
{
    // Per-wave private staging: wave w owns sP[w*768..], sC[w*768..]
    // (192 float4 = 3 KB each). No __syncthreads anywhere — ordering is
    // purely per-wave s_waitcnt. Dense global instructions touch 16
    // lines each instead of 48 at 1/3 density (the round-2/5 limiter:
    // 448 line-events per wave where 176 suffice).
    __shared__ __align__(16) float sP[NWAVES * 768];
    __shared__ __align__(16) float sC[NWAVES * 768];

    const int tid  = threadIdx.x;
    const int lane = tid & 63;
    const int w    = tid >> 6;

    // Lane-resident parameter table: lane l holds M[l] (9 regs) + beta[l].
    float mt[9], bt[3];
    {
        const float* mr = Mg + lane * 9;
#pragma unroll
        for (int k = 0; k < 9; ++k) mt[k] = mr[k];
        const float* br = betag + lane * 3;
#pragma unroll
        for (int k = 0; k < 3; ++k) bt[k] = br[k];
    }

    const float zeps = zeps_p[0];
    const float sf   = sf_p[0];
    const int nt4 = n_edges >> 2;            // 4 edges per thread
    const int t = blockIdx.x * BLOCK + tid;

    if (nt4 > 0) {
        const int NT4F = 3 * nt4;            // total full float4s per array
        const int WB   = 3 * (blockIdx.x * BLOCK + (w << 6)); // wave window
        float* lp = &sP[w * 768];
        float* lc = &sC[w * 768];

        // Dense staging: instr j stages float4s [WB+64j, WB+64j+64) — each
        // global_load_lds_dwordx4 covers 1024 contiguous bytes = 16 lines.
        // Clamp keeps OOB lanes in-bounds (duplicates; stores are guarded).
#pragma unroll
        for (int j = 0; j < 3; ++j) {
            int g = min(WB + j * 64 + lane, NT4F - 1);
            gload_lds16(prnt  + 4 * g, lp + j * 256);
            gload_lds16(child + 4 * g, lc + j * 256);
        }
        // rels: int4/lane at stride 16 — already dense (16 lines/wave).
        int4 r4 = ((const int4*)rels)[min(t, nt4 - 1)];

        // Drain the LDS-DMA before reading the staged data (wave-private
        // region: no barrier needed, just this wave's vmcnt).
        asm volatile("s_waitcnt vmcnt(0)" ::: "memory");

        // Thread's 4 edges = 48 B at byte offset lane*48: 3x ds_read_b128.
        // Bank pattern (quarter-wave, stride 12 dwords): 2-way = free.
        f32x4 pa = *(const f32x4*)(lp + lane * 12);
        f32x4 pb = *(const f32x4*)(lp + lane * 12 + 4);
        f32x4 pc = *(const f32x4*)(lp + lane * 12 + 8);
        f32x4 ca = *(const f32x4*)(lc + lane * 12);
        f32x4 cb = *(const f32x4*)(lc + lane * 12 + 4);
        f32x4 cc = *(const f32x4*)(lc + lane * 12 + 8);

        float P[12] = {pa.x, pa.y, pa.z, pa.w, pb.x, pb.y, pb.z, pb.w,
                       pc.x, pc.y, pc.z, pc.w};
        float C[12] = {ca.x, ca.y, ca.z, ca.w, cb.x, cb.y, cb.z, cb.w,
                       cc.x, cc.y, cc.z, cc.w};
        int R[4] = {r4.x, r4.y, r4.z, r4.w};
        float O[12];
#pragma unroll
        for (int e = 0; e < 4; ++e) {
            int ab = R[e] << 2;              // byte index for bpermute
            float g0 = bperm(ab, mt[0]), g1 = bperm(ab, mt[1]), g2 = bperm(ab, mt[2]);
            float g3 = bperm(ab, mt[3]), g4 = bperm(ab, mt[4]), g5 = bperm(ab, mt[5]);
            float g6 = bperm(ab, mt[6]), g7 = bperm(ab, mt[7]), g8 = bperm(ab, mt[8]);
            float h0 = bperm(ab, bt[0]), h1 = bperm(ab, bt[1]), h2 = bperm(ab, bt[2]);
            edge_core(P[3 * e], P[3 * e + 1], P[3 * e + 2],
                      C[3 * e], C[3 * e + 1], C[3 * e + 2],
                      g0, g1, g2, g3, g4, g5, g6, g7, g8,
                      h0, h1, h2, zeps, sf,
                      O[3 * e], O[3 * e + 1], O[3 * e + 2]);
        }

        // Output transpose through the (now dead) prnt staging region:
        // each lane writes ONLY its own 48 B slot (the slot it just read),
        // so there is no cross-lane WAR hazard.
        *(f32x4*)(lp + lane * 12)     = f32x4{O[0], O[1], O[2],  O[3]};
        *(f32x4*)(lp + lane * 12 + 4) = f32x4{O[4], O[5], O[6],  O[7]};
        *(f32x4*)(lp + lane * 12 + 8) = f32x4{O[8], O[9], O[10], O[11]};
        // Cross-lane readback below: make all lanes' writes visible first.
        asm volatile("s_waitcnt lgkmcnt(0)" ::: "memory");

        // Dense stores: instr j stores float4s [WB+64j+lane] — 16 full
        // lines per instruction (was 48 lines at 1/3 density). Guard
        // g < NT4F also excludes the garbage slots of OOB threads
        // (thread t >= nt4 <=> its float4s >= NT4F).
#pragma unroll
        for (int j = 0; j < 3; ++j) {
            int g = WB + j * 64 + lane;
            if (g < NT4F) {
                f32x4 v = *(const f32x4*)(lp + j * 256 + lane * 4);
                *(f32x4*)(out + 4 * g) = v;
            }
        }
    }

    // Defensive scalar tail for n_edges % 4 (none at N=8M). Divergent:
    // no cross-lane ops — read M/beta straight from global.
    if (blockIdx.x == 0 && threadIdx.x == 0) {
        for (int e = (n_edges >> 2) * 4; e < n_edges; ++e) {
            int r = rels[e];
            const float* m = Mg + r * 9;
            const float* b = betag + r * 3;
            float a0, a1, a2;
            edge_core(prnt[3 * e], prnt[3 * e + 1], prnt[3 * e + 2],
                      child[3 * e], child[3 * e + 1], child[3 * e + 2],
                      m[0], m[1], m[2], m[3], m[4], m[5], m[6], m[7], m[8],
                      b[0], b[1], b[2], zeps, sf, a0, a1, a2);
            out[3 * e] = a0; out[3 * e + 1] = a1; out[3 * e + 2] = a2;
        }
    }
}

extern "C" void kernel_launch(void* const* d_in, const int* in_sizes, int n_in,
                              void* d_out, int out_size, void* d_ws, size_t ws_size,
                              hipStream_t stream) {
    const float* prnt  = (const float*)d_in[0];
    const float* child = (const float*)d_in[1];
    const float* Mg    = (const float*)d_in[2];
    const float* betag = (const float*)d_in[3];
    const float* zeps  = (const float*)d_in[4];
    const float* sf    = (const float*)d_in[5];
    const int*   rels  = (const int*)d_in[6];
    float* out = (float*)d_out;

    int n_edges = in_sizes[0] / 3;
    int nt4 = n_edges >> 2;
    int nblocks = (nt4 + BLOCK - 1) / BLOCK;
    if (nblocks < 1) nblocks = 1;            // tail-only case
    alpha_kernel<<<nblocks, BLOCK, 0, stream>>>(
        prnt, child, Mg, betag, zeps, sf, rels, out, n_edges);
}